// Round 17
// baseline (232.642 us; speedup 1.0000x reference)
//
#include <hip/hip_runtime.h>
#include <hip/hip_bf16.h>
#include <hip/hip_cooperative_groups.h>

namespace cg = cooperative_groups;

#define DD 64
#define ECH 128     // edges per chunk (one-hot GEMM K)
#define NEB 256     // blocks (1/CU, cooperative co-resident)
#define GB 256      // graph bins (B==256)
#define MAXPER 3200 // 25 chunks * 128 >= ceil(E/NEB)=3125

typedef __attribute__((ext_vector_type(8))) short bf16x8_t;
typedef __attribute__((ext_vector_type(4))) float f32x4_t;

__device__ __forceinline__ ushort f2b(float x) {
  __hip_bfloat16 h = __float2bfloat16(x);
  ushort r;
  __builtin_memcpy(&r, &h, 2);
  return r;
}

// XOR swizzle for 256B-row LDS tiles (R13-verified): h=(row&7)^((row>>3)&7).
__device__ __forceinline__ uint swz(uint b) {
  return b ^ (((((b >> 8) & 7u)) ^ ((b >> 11) & 7u)) << 4);
}

// ---------------------------------------------------------------------------
// MLP layer (proven R5..R13, absmax 0.039): MFMA GEMM + bias/ReLU + BN.
// ---------------------------------------------------------------------------
template <int K, int WS, bool FIRST, bool LAST>
__device__ __forceinline__ void mlp_layer(int tid, const ushort* __restrict__ combg,
                                          float* hbuf, ushort* a_lds,
                                          const ushort* w_lds, const float* bias_s,
                                          float* ps, float* pq, float* ab, float* bb,
                                          const float* __restrict__ gamma,
                                          const float* __restrict__ beta,
                                          float* __restrict__ out) {
  const int lane = tid & 63, wv = tid >> 6;
  f32x4_t acc[2][4];
#pragma unroll
  for (int a = 0; a < 2; ++a)
#pragma unroll
    for (int nt = 0; nt < 4; ++nt) acc[a][nt] = (f32x4_t)(0.0f);

  const int m0 = wv * 32;
  const int r15 = lane & 15, kq = lane >> 4;
  for (int kk = 0; kk < K; kk += 32) {
    int koff = kk + kq * 8;
    bf16x8_t af[2], bf[4];
    if (FIRST) {
      const ushort* ap = combg + (size_t)(m0 + r15) * 192 + koff;
      af[0] = *reinterpret_cast<const bf16x8_t*>(ap);
      af[1] = *reinterpret_cast<const bf16x8_t*>(ap + 16 * 192);
    } else {
      const ushort* ap = &a_lds[(m0 + r15) * 72 + koff];
      af[0] = *reinterpret_cast<const bf16x8_t*>(ap);
      af[1] = *reinterpret_cast<const bf16x8_t*>(ap + 16 * 72);
    }
#pragma unroll
    for (int nt = 0; nt < 4; ++nt)
      bf[nt] = *reinterpret_cast<const bf16x8_t*>(&w_lds[(nt * 16 + r15) * WS + koff]);
#pragma unroll
    for (int a = 0; a < 2; ++a)
#pragma unroll
      for (int nt = 0; nt < 4; ++nt)
        acc[a][nt] = __builtin_amdgcn_mfma_f32_16x16x32_bf16(af[a], bf[nt], acc[a][nt], 0, 0, 0);
  }

#pragma unroll
  for (int a = 0; a < 2; ++a) {
#pragma unroll
    for (int nt = 0; nt < 4; ++nt) {
      int col = nt * 16 + r15;
#pragma unroll
      for (int j = 0; j < 4; ++j) {
        int row = m0 + a * 16 + kq * 4 + j;
        float v = acc[a][nt][j] + bias_s[col];
        hbuf[row * 65 + col] = fmaxf(v, 0.f);
      }
    }
  }
  __syncthreads();

  {
    int col = tid & 63, seg = tid >> 6;
    float s = 0.f, q = 0.f;
#pragma unroll
    for (int t = 0; t < 32; ++t) {
      float v = hbuf[(seg * 32 + t) * 65 + col];
      s += v;
      q += v * v;
    }
    ps[seg * 64 + col] = s;
    pq[seg * 64 + col] = q;
  }
  __syncthreads();
  if (tid < 64) {
    float s = 0.f, q = 0.f;
#pragma unroll
    for (int g = 0; g < 8; ++g) {
      s += ps[g * 64 + tid];
      q += pq[g * 64 + tid];
    }
    float mu = s * (1.0f / 256.0f);
    float var = q * (1.0f / 256.0f) - mu * mu;
    float rs = rsqrtf(var + 1e-5f);
    float A = gamma[tid] * rs;
    ab[tid] = A;
    bb[tid] = beta[tid] - mu * A;
  }
  __syncthreads();
  for (int i = tid; i < 256 * 64; i += 512) {
    int r = i >> 6, c = i & 63;
    float y = hbuf[r * 65 + c] * ab[c] + bb[c];
    if (LAST)
      out[i] = y;
    else
      a_lds[r * 72 + c] = f2b(y);
  }
  __syncthreads();
}

// ---------------------------------------------------------------------------
// ONE cooperative kernel: zero-cnt | hist | edgesum(R13) | reduce | MLP.
// 256 blocks x 512 threads, 152.8KB dynamic LDS (1 block/CU).
// R17 fix: __launch_bounds__(512, 2) -- 2 waves/EU = 8 waves/CU = our single
// block -- so the compiler allocates up to 256 VGPR/wave instead of the 80 it
// chose for the (invisible) dynamic-LDS kernel in R16, which spilled
// acc[4][4] to scratch (VGPR=80, WRITE_SIZE 41.7MB vs 17MB expected).
// ---------------------------------------------------------------------------
__global__ __launch_bounds__(512, 2) void k_fused(
    const float* __restrict__ edge_attr, const int* __restrict__ eidx,
    const float* __restrict__ x, const float* __restrict__ u,
    const int* __restrict__ batch,
    const float* __restrict__ W0, const float* __restrict__ b0,
    const float* __restrict__ W1, const float* __restrict__ b1,
    const float* __restrict__ W2, const float* __restrict__ b2,
    const float* __restrict__ g0, const float* __restrict__ be0,
    const float* __restrict__ g1, const float* __restrict__ be1,
    const float* __restrict__ g2, const float* __restrict__ be2,
    float* __restrict__ partial, int* __restrict__ cnt,
    ushort* __restrict__ comb, float* __restrict__ out, int N, int E) {
  extern __shared__ __align__(16) char smem[];
  cg::grid_group grid = cg::this_grid();
  const int tid = threadIdx.x;
  const int bid = blockIdx.x;
  const int gsz = gridDim.x * blockDim.x;
  const int gid = bid * blockDim.x + tid;

  // ---- phase 0: zero cnt ----
  for (int i = gid; i < N; i += gsz) cnt[i] = 0;
  grid.sync();

  // ---- phase 1: histogram ----
  {
    int E4 = E >> 2;
    const int4* e4 = reinterpret_cast<const int4*>(eidx);
    for (int i = gid; i < E4; i += gsz) {
      int4 v = e4[i];
      atomicAdd(&cnt[v.x], 1);
      atomicAdd(&cnt[v.y], 1);
      atomicAdd(&cnt[v.z], 1);
      atomicAdd(&cnt[v.w], 1);
    }
    for (int e = (E4 << 2) + gid; e < E; e += gsz) atomicAdd(&cnt[eidx[e]], 1);
  }
  grid.sync();

  // ---- phase 2: edgesum as split-K one-hot GEMM (R13 verbatim) ----
  {
    ushort* S = (ushort*)smem;             // 64 KB
    ushort* Vt = (ushort*)(smem + 65536);  // 16 KB
    int2* meta = (int2*)(smem + 81920);    // 25.6 KB
    const int lane = tid & 63, wv = tid >> 6;
    const int r15 = lane & 15, kq = lane >> 4;
    const int kh = wv >> 2;  // K-half
    const int mq = wv & 3;   // bin quadrant

    const int per = (E + NEB - 1) / NEB;
    const int base = bid * per;
    const int nE = max(0, min(per, E - base));
    const int nch = (nE + ECH - 1) / ECH;

    const int e0 = (tid >> 3) * 2;
    const int d0 = (tid & 7) * 8;

    float4 rA[4], rB[4];

#define LOADC(c, R)                                                              \
  do {                                                                           \
    size_t r0_ = (size_t)min(base + (c)*ECH + e0, E - 1);                        \
    size_t r1_ = (size_t)min(base + (c)*ECH + e0 + 1, E - 1);                    \
    const float4* p0_ = reinterpret_cast<const float4*>(edge_attr + r0_ * DD + d0); \
    const float4* p1_ = reinterpret_cast<const float4*>(edge_attr + r1_ * DD + d0); \
    R[0] = p0_[0];                                                               \
    R[1] = p0_[1];                                                               \
    R[2] = p1_[0];                                                               \
    R[3] = p1_[1];                                                               \
  } while (0)

#define PHASEW(c, R)                                                             \
  do {                                                                           \
    _Pragma("unroll") for (int q = 0; q < 2; ++q) {                              \
      _Pragma("unroll") for (int j = 0; j < 4; ++j) {                            \
        int d_ = d0 + q * 4 + j;                                                 \
        uint w32_ = (uint)f2b(((const float*)&R[q])[j]) |                        \
                    ((uint)f2b(((const float*)&R[2 + q])[j]) << 16);             \
        *(uint*)((char*)Vt + swz(((uint)d_ * 128 + e0) * 2)) = w32_;             \
      }                                                                          \
    }                                                                            \
    if (tid < ECH) {                                                             \
      if (prev >= 0) *(ushort*)((char*)S + swz(((uint)prev * 128 + tid) * 2)) = 0; \
      int2 mm_ = meta[(c)*ECH + tid];                                            \
      if (mm_.x >= 0) {                                                          \
        *(ushort*)((char*)S + swz(((uint)mm_.x * 128 + tid) * 2)) =              \
            f2b(__int_as_float(mm_.y));                                          \
        prev = mm_.x;                                                            \
      } else {                                                                   \
        prev = -1;                                                               \
      }                                                                          \
    }                                                                            \
  } while (0)

#define MFMAP()                                                                  \
  do {                                                                           \
    _Pragma("unroll") for (int ks = 0; ks < 2; ++ks) {                           \
      uint ko_ = (uint)((kh * 2 + ks) * 32 + kq * 8) * 2;                        \
      bf16x8_t b0_ = *(const bf16x8_t*)((const char*)Vt + swz((uint)(r15)*256 + ko_)); \
      bf16x8_t b1_ = *(const bf16x8_t*)((const char*)Vt +                        \
                                        swz((uint)(16 + r15) * 256 + ko_));      \
      bf16x8_t b2_ = *(const bf16x8_t*)((const char*)Vt +                        \
                                        swz((uint)(32 + r15) * 256 + ko_));      \
      bf16x8_t b3_ = *(const bf16x8_t*)((const char*)Vt +                        \
                                        swz((uint)(48 + r15) * 256 + ko_));      \
      _Pragma("unroll") for (int mt = 0; mt < 4; ++mt) {                         \
        bf16x8_t a_ = *(const bf16x8_t*)((const char*)S +                        \
                                         swz((uint)(mq * 64 + mt * 16 + r15) * 256 + ko_)); \
        acc[mt][0] = __builtin_amdgcn_mfma_f32_16x16x32_bf16(a_, b0_, acc[mt][0], 0, 0, 0); \
        acc[mt][1] = __builtin_amdgcn_mfma_f32_16x16x32_bf16(a_, b1_, acc[mt][1], 0, 0, 0); \
        acc[mt][2] = __builtin_amdgcn_mfma_f32_16x16x32_bf16(a_, b2_, acc[mt][2], 0, 0, 0); \
        acc[mt][3] = __builtin_amdgcn_mfma_f32_16x16x32_bf16(a_, b3_, acc[mt][3], 0, 0, 0); \
      }                                                                          \
    }                                                                            \
  } while (0)

#define LGKM0() asm volatile("s_waitcnt lgkmcnt(0)" ::: "memory")

    f32x4_t acc[4][4];
#pragma unroll
    for (int a = 0; a < 4; ++a)
#pragma unroll
      for (int nt = 0; nt < 4; ++nt) acc[a][nt] = (f32x4_t)(0.0f);

    if (nch > 0) LOADC(0, rA);
    if (nch > 1) LOADC(1, rB);
    for (int i = tid; i < 256 * 128 / 2; i += 512) ((uint*)S)[i] = 0u;
    for (int i = tid; i < MAXPER; i += 512) {
      int pb = -1;
      float pw = 0.f;
      if (i < nE) {
        int n = eidx[base + i];
        pw = 1.0f / fmaxf((float)cnt[n], 1.0f);
        pb = batch[n];
      }
      meta[i] = make_int2(pb, __float_as_int(pw));
    }
    int prev = -1;
    __syncthreads();

    for (int c = 0; c < nch; c += 2) {
      PHASEW(c, rA);
      LGKM0();
      __builtin_amdgcn_s_barrier();
      if (c + 2 < nch) LOADC(c + 2, rA);
      MFMAP();
      LGKM0();
      __builtin_amdgcn_s_barrier();
      if (c + 1 < nch) {
        PHASEW(c + 1, rB);
        LGKM0();
        __builtin_amdgcn_s_barrier();
        if (c + 3 < nch) LOADC(c + 3, rB);
        MFMAP();
        LGKM0();
        __builtin_amdgcn_s_barrier();
      }
    }

    // merge K-half partials through LDS (D layout m89: col=lane&15, row=(lane>>4)*4+j)
    __syncthreads();
    float* Smrg = (float*)S;
    if (kh == 0) {
#pragma unroll
      for (int mt = 0; mt < 4; ++mt)
#pragma unroll
        for (int nt = 0; nt < 4; ++nt)
#pragma unroll
          for (int j = 0; j < 4; ++j)
            Smrg[(mq * 64 + mt * 16 + kq * 4 + j) * 64 + nt * 16 + r15] = acc[mt][nt][j];
    }
    __syncthreads();
    if (kh == 1) {
      float* outp = partial + (size_t)bid * GB * DD;
#pragma unroll
      for (int mt = 0; mt < 4; ++mt)
#pragma unroll
        for (int nt = 0; nt < 4; ++nt)
#pragma unroll
          for (int j = 0; j < 4; ++j) {
            int idx = (mq * 64 + mt * 16 + kq * 4 + j) * 64 + nt * 16 + r15;
            outp[idx] = Smrg[idx] + acc[mt][nt][j];
          }
    }
#undef LOADC
#undef PHASEW
#undef MFMAP
#undef LGKM0
  }
  grid.sync();

  // ---- phase 3: per-graph reduce (block b = graph b) ----
  {
    __shared__ int s_lo, s_hi;
    __shared__ float rE[8][64], rV[8][64];
    int b = bid;
    if (tid == 0) {
      int lo = 0, hi = N;
      while (lo < hi) { int m = (lo + hi) >> 1; if (batch[m] < b) lo = m + 1; else hi = m; }
      s_lo = lo;
      hi = N;
      while (lo < hi) { int m = (lo + hi) >> 1; if (batch[m] < b + 1) lo = m + 1; else hi = m; }
      s_hi = lo;
    }
    __syncthreads();
    int lo = s_lo, hi = s_hi;
    int d = tid & 63, sub = tid >> 6;
    float accE = 0.f, accV = 0.f;
    for (int p = sub; p < NEB; p += 8)
      accE += partial[((size_t)p * GB + b) * DD + d];
    for (int n = lo + sub; n < hi; n += 8)
      accV += x[(size_t)n * DD + d];
    rE[sub][d] = accE;
    rV[sub][d] = accV;
    __syncthreads();
    if (tid < 64) {
      float sE = 0.f, sV = 0.f;
#pragma unroll
      for (int g = 0; g < 8; ++g) {
        sE += rE[g][tid];
        sV += rV[g][tid];
      }
      float invNb = 1.0f / fmaxf((float)(hi - lo), 1.0f);
      ushort* row = comb + (size_t)b * 192;
      row[tid] = f2b(sE * invNb);
      row[64 + tid] = f2b(sV * invNb);
      row[128 + tid] = f2b(u[(size_t)b * DD + tid]);
    }
  }
  grid.sync();

  // ---- phase 4: block 0 runs the fused MLP ----
  if (bid == 0) {
    float* hbuf = (float*)smem;                    // 66,560 B
    ushort* a_lds = (ushort*)(smem + 66560);       // 36,864 B
    ushort* w0s = (ushort*)(smem + 103424);        // 25,600 B
    ushort* w1s = (ushort*)(smem + 129024);        // 9,216 B
    ushort* w2s = (ushort*)(smem + 138240);        // 9,216 B
    float* ps = (float*)(smem + 147456);           // 2,048 B
    float* pq = (float*)(smem + 149504);           // 2,048 B
    float* b0s = (float*)(smem + 151552);
    float* b1s = (float*)(smem + 151808);
    float* b2s = (float*)(smem + 152064);
    float* ab = (float*)(smem + 152320);
    float* bb = (float*)(smem + 152576);

    __syncthreads();  // phase-3 LDS use done before overwrite
    for (int i = tid; i < 64 * 192; i += 512) {
      int r = i / 192, c = i - r * 192;
      w0s[r * 200 + c] = f2b(W0[i]);
    }
    for (int i = tid; i < 64 * 64; i += 512) {
      int r = i >> 6, c = i & 63;
      w1s[r * 72 + c] = f2b(W1[i]);
      w2s[r * 72 + c] = f2b(W2[i]);
    }
    if (tid < 64) {
      b0s[tid] = b0[tid];
      b1s[tid] = b1[tid];
      b2s[tid] = b2[tid];
    }
    __syncthreads();

    mlp_layer<192, 200, true, false>(tid, comb, hbuf, a_lds, w0s, b0s, ps, pq, ab, bb,
                                     g0, be0, nullptr);
    mlp_layer<64, 72, false, false>(tid, comb, hbuf, a_lds, w1s, b1s, ps, pq, ab, bb,
                                    g1, be1, nullptr);
    mlp_layer<64, 72, false, true>(tid, comb, hbuf, a_lds, w2s, b2s, ps, pq, ab, bb,
                                   g2, be2, out);
  }
}

extern "C" void kernel_launch(void* const* d_in, const int* in_sizes, int n_in,
                              void* d_out, int out_size, void* d_ws, size_t ws_size,
                              hipStream_t stream) {
  (void)n_in; (void)out_size; (void)ws_size;
  const float* edge_attr = (const float*)d_in[1];
  const float* x         = (const float*)d_in[0];
  const float* u         = (const float*)d_in[2];
  const int*   eidx      = (const int*)d_in[3];  // row 0 = first E entries
  const int*   batch     = (const int*)d_in[4];
  const float* W0 = (const float*)d_in[5];
  const float* b0 = (const float*)d_in[6];
  const float* W1 = (const float*)d_in[7];
  const float* b1 = (const float*)d_in[8];
  const float* W2 = (const float*)d_in[9];
  const float* b2 = (const float*)d_in[10];
  const float* g0 = (const float*)d_in[11];
  const float* be0 = (const float*)d_in[12];
  const float* g1 = (const float*)d_in[13];
  const float* be1 = (const float*)d_in[14];
  const float* g2 = (const float*)d_in[15];
  const float* be2 = (const float*)d_in[16];

  int N = in_sizes[0] / DD;
  int E = in_sizes[1] / DD;

  // ws: partial[NEB*GB*64] f32 (16.7MB) | cnt[N] | comb[256*192 bf16]
  float* partial = (float*)d_ws;
  int* cnt = (int*)(partial + (size_t)NEB * GB * DD);
  ushort* comb = (ushort*)(cnt + ((N + 3) & ~3));
  float* out = (float*)d_out;

  void* args[] = {&edge_attr, &eidx, &x, &u, &batch,
                  &W0, &b0, &W1, &b1, &W2, &b2,
                  &g0, &be0, &g1, &be1, &g2, &be2,
                  &partial, &cnt, &comb, &out, &N, &E};
  hipLaunchCooperativeKernel(reinterpret_cast<void*>(k_fused), dim3(NEB), dim3(512),
                             args, 152832, stream);
}

// Round 18
// 142.077 us; speedup vs baseline: 1.6374x; 1.6374x over previous
//
#include <hip/hip_runtime.h>
#include <hip/hip_bf16.h>

#define DD 64
#define ECH 128     // edges per chunk (one-hot GEMM K)
#define NEB 256     // edgesum blocks (1 per CU)
#define GB 256      // graph bins (B==256)
#define MAXPER 3200 // 25 chunks * 128 >= ceil(E/NEB)=3125

typedef __attribute__((ext_vector_type(8))) short bf16x8_t;
typedef __attribute__((ext_vector_type(4))) float f32x4_t;

__device__ __forceinline__ ushort f2b(float x) {
  __hip_bfloat16 h = __float2bfloat16(x);
  ushort r;
  __builtin_memcpy(&r, &h, 2);
  return r;
}

// XOR swizzle for 256B-row LDS tiles. h = (row&7) ^ ((row>>3)&7):
//  * fragment reads (16 consecutive rows per lane-group): 2-way (free)
//  * transpose writes (row stride 8 within an instruction): banks spread
__device__ __forceinline__ uint swz(uint b) {
  return b ^ (((((b >> 8) & 7u)) ^ ((b >> 11) & 7u)) << 4);
}

__global__ __launch_bounds__(256) void k_zero(int* __restrict__ p, int n) {
  int gid = blockIdx.x * blockDim.x + threadIdx.x;
  int stride = gridDim.x * blockDim.x;
  for (int i = gid; i < n; i += stride) p[i] = 0;
}

__global__ __launch_bounds__(256) void k_hist(const int* __restrict__ eidx,
                                              int* __restrict__ cnt, int E) {
  int gid = blockIdx.x * blockDim.x + threadIdx.x;
  int stride = gridDim.x * blockDim.x;
  int E4 = E >> 2;
  const int4* e4 = reinterpret_cast<const int4*>(eidx);
  for (int i = gid; i < E4; i += stride) {
    int4 v = e4[i];
    atomicAdd(&cnt[v.x], 1);
    atomicAdd(&cnt[v.y], 1);
    atomicAdd(&cnt[v.z], 1);
    atomicAdd(&cnt[v.w], 1);
  }
  for (int e = (E4 << 2) + gid; e < E; e += stride) atomicAdd(&cnt[eidx[e]], 1);
}

// ---------------------------------------------------------------------------
// Edge -> graph-bin accumulation as ONE-HOT GEMM per chunk (R13, best-known):
//   C[256 bins][64 dims] += S[256][128] * V  where S[b][e] = w_e one-hot.
//  * swizzled S/Vt rows (write- and read-conflict-free)
//  * SPLIT-K: waves 0-3 own K 0..63, waves 4-7 own K 64..127; each wave
//    computes 64 bins x 64 dims (4 m-tiles) -> 16 fragment reads/chunk/wave.
//    Wave pairs merge through LDS (S reused) at epilogue.
// LDS: S 64KB + Vt 16KB + meta 25.6KB = 105.6KB -> 1 block/CU.
// ---------------------------------------------------------------------------
__global__ __launch_bounds__(512) void k_edgesum(const float* __restrict__ edge_attr,
                                                 const int* __restrict__ eidx,
                                                 const int* __restrict__ cnt,
                                                 const int* __restrict__ batch,
                                                 float* __restrict__ partial, int E) {
  __shared__ ushort S[256 * 128];  // 64 KB, rows = bins, 256B/row
  __shared__ ushort Vt[64 * 128];  // 16 KB, rows = dims,  256B/row
  __shared__ int2 meta[MAXPER];    // 25.6 KB
  const int tid = threadIdx.x;
  const int lane = tid & 63, wv = tid >> 6;
  const int r15 = lane & 15, kq = lane >> 4;
  const int kh = wv >> 2;  // K-half this wave contracts (0: e 0..63, 1: 64..127)
  const int mq = wv & 3;   // bin quadrant: bins [mq*64, mq*64+64)

  const int per = (E + NEB - 1) / NEB;        // 3125
  const int base = blockIdx.x * per;
  const int nE = max(0, min(per, E - base));
  const int nch = (nE + ECH - 1) / ECH;       // 25

  const int e0 = (tid >> 3) * 2;  // edge pair owned by this thread
  const int d0 = (tid & 7) * 8;   // dim group owned by this thread

  float4 rA[4], rB[4];

#define LOADC(c, R)                                                              \
  do {                                                                           \
    size_t r0_ = (size_t)min(base + (c)*ECH + e0, E - 1);                        \
    size_t r1_ = (size_t)min(base + (c)*ECH + e0 + 1, E - 1);                    \
    const float4* p0_ = reinterpret_cast<const float4*>(edge_attr + r0_ * DD + d0); \
    const float4* p1_ = reinterpret_cast<const float4*>(edge_attr + r1_ * DD + d0); \
    R[0] = p0_[0];                                                               \
    R[1] = p0_[1];                                                               \
    R[2] = p1_[0];                                                               \
    R[3] = p1_[1];                                                               \
  } while (0)

#define PHASEW(c, R)                                                             \
  do {                                                                           \
    _Pragma("unroll") for (int q = 0; q < 2; ++q) {                              \
      _Pragma("unroll") for (int j = 0; j < 4; ++j) {                            \
        int d_ = d0 + q * 4 + j;                                                 \
        uint w32_ = (uint)f2b(((const float*)&R[q])[j]) |                        \
                    ((uint)f2b(((const float*)&R[2 + q])[j]) << 16);             \
        *(uint*)((char*)Vt + swz(((uint)d_ * 128 + e0) * 2)) = w32_;             \
      }                                                                          \
    }                                                                            \
    if (tid < ECH) {                                                             \
      if (prev >= 0) *(ushort*)((char*)S + swz(((uint)prev * 128 + tid) * 2)) = 0; \
      int2 mm_ = meta[(c)*ECH + tid];                                            \
      if (mm_.x >= 0) {                                                          \
        *(ushort*)((char*)S + swz(((uint)mm_.x * 128 + tid) * 2)) =              \
            f2b(__int_as_float(mm_.y));                                          \
        prev = mm_.x;                                                            \
      } else {                                                                   \
        prev = -1;                                                               \
      }                                                                          \
    }                                                                            \
  } while (0)

// split-K MFMA phase: this wave's 2 k-steps over 4 m-tiles x 4 n-tiles
#define MFMAP()                                                                  \
  do {                                                                           \
    _Pragma("unroll") for (int ks = 0; ks < 2; ++ks) {                           \
      uint ko_ = (uint)((kh * 2 + ks) * 32 + kq * 8) * 2;                        \
      bf16x8_t b0_ = *(const bf16x8_t*)((const char*)Vt + swz((uint)(r15)*256 + ko_)); \
      bf16x8_t b1_ = *(const bf16x8_t*)((const char*)Vt +                        \
                                        swz((uint)(16 + r15) * 256 + ko_));      \
      bf16x8_t b2_ = *(const bf16x8_t*)((const char*)Vt +                        \
                                        swz((uint)(32 + r15) * 256 + ko_));      \
      bf16x8_t b3_ = *(const bf16x8_t*)((const char*)Vt +                        \
                                        swz((uint)(48 + r15) * 256 + ko_));      \
      _Pragma("unroll") for (int mt = 0; mt < 4; ++mt) {                         \
        bf16x8_t a_ = *(const bf16x8_t*)((const char*)S +                        \
                                         swz((uint)(mq * 64 + mt * 16 + r15) * 256 + ko_)); \
        acc[mt][0] = __builtin_amdgcn_mfma_f32_16x16x32_bf16(a_, b0_, acc[mt][0], 0, 0, 0); \
        acc[mt][1] = __builtin_amdgcn_mfma_f32_16x16x32_bf16(a_, b1_, acc[mt][1], 0, 0, 0); \
        acc[mt][2] = __builtin_amdgcn_mfma_f32_16x16x32_bf16(a_, b2_, acc[mt][2], 0, 0, 0); \
        acc[mt][3] = __builtin_amdgcn_mfma_f32_16x16x32_bf16(a_, b3_, acc[mt][3], 0, 0, 0); \
      }                                                                          \
    }                                                                            \
  } while (0)

#define LGKM0() asm volatile("s_waitcnt lgkmcnt(0)" ::: "memory")

  f32x4_t acc[4][4];
#pragma unroll
  for (int a = 0; a < 4; ++a)
#pragma unroll
    for (int nt = 0; nt < 4; ++nt) acc[a][nt] = (f32x4_t)(0.0f);

  // prologue: fire chunk 0/1 loads early, then meta + S zero
  LOADC(0, rA);
  if (nch > 1) LOADC(1, rB);
  for (int i = tid; i < 256 * 128 / 2; i += 512) ((uint*)S)[i] = 0u;
  for (int i = tid; i < MAXPER; i += 512) {
    int pb = -1;
    float pw = 0.f;
    if (i < nE) {
      int n = eidx[base + i];
      pw = 1.0f / fmaxf((float)cnt[n], 1.0f);
      pb = batch[n];
    }
    meta[i] = make_int2(pb, __float_as_int(pw));
  }
  int prev = -1;
  __syncthreads();

  for (int c = 0; c < nch; c += 2) {
    PHASEW(c, rA);
    LGKM0();
    __builtin_amdgcn_s_barrier();
    if (c + 2 < nch) LOADC(c + 2, rA);
    MFMAP();
    LGKM0();
    __builtin_amdgcn_s_barrier();
    if (c + 1 < nch) {
      PHASEW(c + 1, rB);
      LGKM0();
      __builtin_amdgcn_s_barrier();
      if (c + 3 < nch) LOADC(c + 3, rB);
      MFMAP();
      LGKM0();
      __builtin_amdgcn_s_barrier();
    }
  }

  // epilogue: merge K-half partials through LDS (S is free now), then store.
  // D layout (16x16x32): col = lane&15, row = (lane>>4)*4 + j  [m89]
  __syncthreads();
  float* Smrg = (float*)S;  // 256*64 f32 = 64KB
  if (kh == 0) {
#pragma unroll
    for (int mt = 0; mt < 4; ++mt)
#pragma unroll
      for (int nt = 0; nt < 4; ++nt)
#pragma unroll
        for (int j = 0; j < 4; ++j)
          Smrg[(mq * 64 + mt * 16 + kq * 4 + j) * 64 + nt * 16 + r15] = acc[mt][nt][j];
  }
  __syncthreads();
  if (kh == 1) {
    float* outp = partial + (size_t)blockIdx.x * GB * DD;
#pragma unroll
    for (int mt = 0; mt < 4; ++mt)
#pragma unroll
      for (int nt = 0; nt < 4; ++nt)
#pragma unroll
        for (int j = 0; j < 4; ++j) {
          int idx = (mq * 64 + mt * 16 + kq * 4 + j) * 64 + nt * 16 + r15;
          outp[idx] = Smrg[idx] + acc[mt][nt][j];
        }
  }
#undef LOADC
#undef PHASEW
#undef MFMAP
#undef LGKM0
}

// ---------------------------------------------------------------------------
// Per-graph: reduce NEB partials + pool x + copy u -> bf16 comb row.
// ---------------------------------------------------------------------------
__global__ __launch_bounds__(256) void k_reduce(const float* __restrict__ partial,
                                                const float* __restrict__ x,
                                                const float* __restrict__ u,
                                                const int* __restrict__ batch,
                                                ushort* __restrict__ comb, int N) {
  __shared__ int s_lo, s_hi;
  __shared__ float rE[4][64], rV[4][64];
  int b = blockIdx.x;
  int tid = threadIdx.x;
  if (tid == 0) {
    int lo = 0, hi = N;
    while (lo < hi) { int m = (lo + hi) >> 1; if (batch[m] < b) lo = m + 1; else hi = m; }
    s_lo = lo;
    hi = N;
    while (lo < hi) { int m = (lo + hi) >> 1; if (batch[m] < b + 1) lo = m + 1; else hi = m; }
    s_hi = lo;
  }
  __syncthreads();
  int lo = s_lo, hi = s_hi;
  int d = tid & 63, sub = tid >> 6;
  float accE = 0.f, accV = 0.f;
  for (int p = sub; p < NEB; p += 4)
    accE += partial[((size_t)p * GB + b) * DD + d];
  for (int n = lo + sub; n < hi; n += 4)
    accV += x[(size_t)n * DD + d];
  rE[sub][d] = accE;
  rV[sub][d] = accV;
  __syncthreads();
  if (sub == 0) {
    float invNb = 1.0f / fmaxf((float)(hi - lo), 1.0f);
    float ue = (rE[0][d] + rE[1][d] + rE[2][d] + rE[3][d]) * invNb;
    float uv = (rV[0][d] + rV[1][d] + rV[2][d] + rV[3][d]) * invNb;
    ushort* row = comb + (size_t)b * 192;
    row[d] = f2b(ue);
    row[64 + d] = f2b(uv);
    row[128 + d] = f2b(u[(size_t)b * DD + d]);
  }
}

// ---------------------------------------------------------------------------
// MFMA MLP: 1 block, 512 threads (8 waves), all weights pre-staged behind one
// barrier. Proven (absmax 0.039 << 0.13).
// ---------------------------------------------------------------------------
template <int K, int WS, bool FIRST, bool LAST>
__device__ __forceinline__ void mlp_layer(int tid, const ushort* __restrict__ combg,
                                          float* hbuf, ushort* a_lds,
                                          const ushort* w_lds, const float* bias_s,
                                          float* ps, float* pq, float* ab, float* bb,
                                          const float* __restrict__ gamma,
                                          const float* __restrict__ beta,
                                          float* __restrict__ out) {
  const int lane = tid & 63, wv = tid >> 6;
  f32x4_t acc[2][4];
#pragma unroll
  for (int a = 0; a < 2; ++a)
#pragma unroll
    for (int nt = 0; nt < 4; ++nt) acc[a][nt] = (f32x4_t)(0.0f);

  const int m0 = wv * 32;
  const int r15 = lane & 15, kq = lane >> 4;
  for (int kk = 0; kk < K; kk += 32) {
    int koff = kk + kq * 8;
    bf16x8_t af[2], bf[4];
    if (FIRST) {
      const ushort* ap = combg + (size_t)(m0 + r15) * 192 + koff;
      af[0] = *reinterpret_cast<const bf16x8_t*>(ap);
      af[1] = *reinterpret_cast<const bf16x8_t*>(ap + 16 * 192);
    } else {
      const ushort* ap = &a_lds[(m0 + r15) * 72 + koff];
      af[0] = *reinterpret_cast<const bf16x8_t*>(ap);
      af[1] = *reinterpret_cast<const bf16x8_t*>(ap + 16 * 72);
    }
#pragma unroll
    for (int nt = 0; nt < 4; ++nt)
      bf[nt] = *reinterpret_cast<const bf16x8_t*>(&w_lds[(nt * 16 + r15) * WS + koff]);
#pragma unroll
    for (int a = 0; a < 2; ++a)
#pragma unroll
      for (int nt = 0; nt < 4; ++nt)
        acc[a][nt] = __builtin_amdgcn_mfma_f32_16x16x32_bf16(af[a], bf[nt], acc[a][nt], 0, 0, 0);
  }

#pragma unroll
  for (int a = 0; a < 2; ++a) {
#pragma unroll
    for (int nt = 0; nt < 4; ++nt) {
      int col = nt * 16 + r15;
#pragma unroll
      for (int j = 0; j < 4; ++j) {
        int row = m0 + a * 16 + kq * 4 + j;
        float v = acc[a][nt][j] + bias_s[col];
        hbuf[row * 65 + col] = fmaxf(v, 0.f);
      }
    }
  }
  __syncthreads();

  {
    int col = tid & 63, seg = tid >> 6;
    float s = 0.f, q = 0.f;
#pragma unroll
    for (int t = 0; t < 32; ++t) {
      float v = hbuf[(seg * 32 + t) * 65 + col];
      s += v;
      q += v * v;
    }
    ps[seg * 64 + col] = s;
    pq[seg * 64 + col] = q;
  }
  __syncthreads();
  if (tid < 64) {
    float s = 0.f, q = 0.f;
#pragma unroll
    for (int g = 0; g < 8; ++g) {
      s += ps[g * 64 + tid];
      q += pq[g * 64 + tid];
    }
    float mu = s * (1.0f / 256.0f);
    float var = q * (1.0f / 256.0f) - mu * mu;
    float rs = rsqrtf(var + 1e-5f);
    float A = gamma[tid] * rs;
    ab[tid] = A;
    bb[tid] = beta[tid] - mu * A;
  }
  __syncthreads();
  for (int i = tid; i < 256 * 64; i += 512) {
    int r = i >> 6, c = i & 63;
    float y = hbuf[r * 65 + c] * ab[c] + bb[c];
    if (LAST)
      out[i] = y;
    else
      a_lds[r * 72 + c] = f2b(y);
  }
  __syncthreads();
}

__global__ __launch_bounds__(512) void k_mlp(const ushort* __restrict__ comb,
                                             const float* W0, const float* b0,
                                             const float* W1, const float* b1,
                                             const float* W2, const float* b2,
                                             const float* g0, const float* be0,
                                             const float* g1, const float* be1,
                                             const float* g2, const float* be2,
                                             float* __restrict__ out) {
  __shared__ __align__(16) float hbuf[256 * 65];    // 66.6 KB
  __shared__ __align__(16) ushort a_lds[256 * 72];  // 36.9 KB
  __shared__ __align__(16) ushort w0s[64 * 200];    // 25.6 KB
  __shared__ __align__(16) ushort w1s[64 * 72];     // 9.2 KB
  __shared__ __align__(16) ushort w2s[64 * 72];     // 9.2 KB
  __shared__ float ps[8 * 64], pq[8 * 64];
  __shared__ float b0s[64], b1s[64], b2s[64], ab[64], bb[64];
  int tid = threadIdx.x;

  for (int i = tid; i < 64 * 192; i += 512) {
    int r = i / 192, c = i - r * 192;
    w0s[r * 200 + c] = f2b(W0[i]);
  }
  for (int i = tid; i < 64 * 64; i += 512) {
    int r = i >> 6, c = i & 63;
    w1s[r * 72 + c] = f2b(W1[i]);
    w2s[r * 72 + c] = f2b(W2[i]);
  }
  if (tid < 64) {
    b0s[tid] = b0[tid];
    b1s[tid] = b1[tid];
    b2s[tid] = b2[tid];
  }
  __syncthreads();

  mlp_layer<192, 200, true, false>(tid, comb, hbuf, a_lds, w0s, b0s, ps, pq, ab, bb,
                                   g0, be0, nullptr);
  mlp_layer<64, 72, false, false>(tid, comb, hbuf, a_lds, w1s, b1s, ps, pq, ab, bb,
                                  g1, be1, nullptr);
  mlp_layer<64, 72, false, true>(tid, comb, hbuf, a_lds, w2s, b2s, ps, pq, ab, bb,
                                 g2, be2, out);
}

extern "C" void kernel_launch(void* const* d_in, const int* in_sizes, int n_in,
                              void* d_out, int out_size, void* d_ws, size_t ws_size,
                              hipStream_t stream) {
  (void)n_in; (void)out_size; (void)ws_size;
  const float* x         = (const float*)d_in[0];
  const float* edge_attr = (const float*)d_in[1];
  const float* u         = (const float*)d_in[2];
  const int*   eidx      = (const int*)d_in[3];  // row 0 = first E entries
  const int*   batch     = (const int*)d_in[4];
  const float* W0 = (const float*)d_in[5];
  const float* b0 = (const float*)d_in[6];
  const float* W1 = (const float*)d_in[7];
  const float* b1 = (const float*)d_in[8];
  const float* W2 = (const float*)d_in[9];
  const float* b2 = (const float*)d_in[10];
  const float* g0 = (const float*)d_in[11];
  const float* be0 = (const float*)d_in[12];
  const float* g1 = (const float*)d_in[13];
  const float* be1 = (const float*)d_in[14];
  const float* g2 = (const float*)d_in[15];
  const float* be2 = (const float*)d_in[16];

  int N = in_sizes[0] / DD;
  int E = in_sizes[1] / DD;

  // ws layout (16B padded): partial[NEB*GB*64] f32 (16.7MB) | cnt[N] | comb
  float* partial = (float*)d_ws;
  int* cnt = (int*)(partial + (size_t)NEB * GB * DD);
  ushort* comb = (ushort*)(cnt + ((N + 3) & ~3));

  k_zero<<<64, 256, 0, stream>>>(cnt, N);
  k_hist<<<2048, 256, 0, stream>>>(eidx, cnt, E);
  k_edgesum<<<NEB, 512, 0, stream>>>(edge_attr, eidx, cnt, batch, partial, E);
  k_reduce<<<256, 256, 0, stream>>>(partial, x, u, batch, comb, N);
  k_mlp<<<1, 512, 0, stream>>>(comb, W0, b0, W1, b1, W2, b2,
                               g0, be0, g1, be1, g2, be2, (float*)d_out);
}

// Round 19
// 136.202 us; speedup vs baseline: 1.7081x; 1.0431x over previous
//
#include <hip/hip_runtime.h>
#include <hip/hip_bf16.h>

#define DD 64
#define ECH 128     // edges per chunk (one-hot GEMM K)
#define NEB 256     // edgesum blocks (1 per CU)
#define GB 256      // graph bins (B==256)
#define MAXPER 3200 // 25 chunks * 128 >= ceil(E/NEB)=3125

typedef __attribute__((ext_vector_type(8))) short bf16x8_t;
typedef __attribute__((ext_vector_type(4))) float f32x4_t;

__device__ __forceinline__ ushort f2b(float x) {
  __hip_bfloat16 h = __float2bfloat16(x);
  ushort r;
  __builtin_memcpy(&r, &h, 2);
  return r;
}

// XOR swizzle for 256B-row LDS tiles. h = (row&7) ^ ((row>>3)&7):
//  * fragment reads (16 consecutive rows per lane-group): 2-way (free)
//  * transpose writes (row stride 8 within an instruction): banks spread
__device__ __forceinline__ uint swz(uint b) {
  return b ^ (((((b >> 8) & 7u)) ^ ((b >> 11) & 7u)) << 4);
}

__global__ __launch_bounds__(256) void k_zero(int* __restrict__ p, int n) {
  int gid = blockIdx.x * blockDim.x + threadIdx.x;
  int stride = gridDim.x * blockDim.x;
  for (int i = gid; i < n; i += stride) p[i] = 0;
}

__global__ __launch_bounds__(256) void k_hist(const int* __restrict__ eidx,
                                              int* __restrict__ cnt, int E) {
  int gid = blockIdx.x * blockDim.x + threadIdx.x;
  int stride = gridDim.x * blockDim.x;
  int E4 = E >> 2;
  const int4* e4 = reinterpret_cast<const int4*>(eidx);
  for (int i = gid; i < E4; i += stride) {
    int4 v = e4[i];
    atomicAdd(&cnt[v.x], 1);
    atomicAdd(&cnt[v.y], 1);
    atomicAdd(&cnt[v.z], 1);
    atomicAdd(&cnt[v.w], 1);
  }
  for (int e = (E4 << 2) + gid; e < E; e += stride) atomicAdd(&cnt[eidx[e]], 1);
}

// ---------------------------------------------------------------------------
// Edge -> graph-bin accumulation as ONE-HOT GEMM per chunk (R13, best-known):
//   C[256 bins][64 dims] += S[256][128] * V  where S[b][e] = w_e one-hot.
//  * swizzled S/Vt rows (write- and read-conflict-free)
//  * SPLIT-K: waves 0-3 own K 0..63, waves 4-7 own K 64..127; each wave
//    computes 64 bins x 64 dims (4 m-tiles) -> 16 fragment reads/chunk/wave.
//    Wave pairs merge through LDS (S reused) at epilogue.
// LDS: S 64KB + Vt 16KB + meta 25.6KB = 105.6KB -> 1 block/CU.
// ---------------------------------------------------------------------------
__global__ __launch_bounds__(512) void k_edgesum(const float* __restrict__ edge_attr,
                                                 const int* __restrict__ eidx,
                                                 const int* __restrict__ cnt,
                                                 const int* __restrict__ batch,
                                                 float* __restrict__ partial, int E) {
  __shared__ ushort S[256 * 128];  // 64 KB, rows = bins, 256B/row
  __shared__ ushort Vt[64 * 128];  // 16 KB, rows = dims,  256B/row
  __shared__ int2 meta[MAXPER];    // 25.6 KB
  const int tid = threadIdx.x;
  const int lane = tid & 63, wv = tid >> 6;
  const int r15 = lane & 15, kq = lane >> 4;
  const int kh = wv >> 2;  // K-half this wave contracts (0: e 0..63, 1: 64..127)
  const int mq = wv & 3;   // bin quadrant: bins [mq*64, mq*64+64)

  const int per = (E + NEB - 1) / NEB;        // 3125
  const int base = blockIdx.x * per;
  const int nE = max(0, min(per, E - base));
  const int nch = (nE + ECH - 1) / ECH;       // 25

  const int e0 = (tid >> 3) * 2;  // edge pair owned by this thread
  const int d0 = (tid & 7) * 8;   // dim group owned by this thread

  float4 rA[4], rB[4];

#define LOADC(c, R)                                                              \
  do {                                                                           \
    size_t r0_ = (size_t)min(base + (c)*ECH + e0, E - 1);                        \
    size_t r1_ = (size_t)min(base + (c)*ECH + e0 + 1, E - 1);                    \
    const float4* p0_ = reinterpret_cast<const float4*>(edge_attr + r0_ * DD + d0); \
    const float4* p1_ = reinterpret_cast<const float4*>(edge_attr + r1_ * DD + d0); \
    R[0] = p0_[0];                                                               \
    R[1] = p0_[1];                                                               \
    R[2] = p1_[0];                                                               \
    R[3] = p1_[1];                                                               \
  } while (0)

#define PHASEW(c, R)                                                             \
  do {                                                                           \
    _Pragma("unroll") for (int q = 0; q < 2; ++q) {                              \
      _Pragma("unroll") for (int j = 0; j < 4; ++j) {                            \
        int d_ = d0 + q * 4 + j;                                                 \
        uint w32_ = (uint)f2b(((const float*)&R[q])[j]) |                        \
                    ((uint)f2b(((const float*)&R[2 + q])[j]) << 16);             \
        *(uint*)((char*)Vt + swz(((uint)d_ * 128 + e0) * 2)) = w32_;             \
      }                                                                          \
    }                                                                            \
    if (tid < ECH) {                                                             \
      if (prev >= 0) *(ushort*)((char*)S + swz(((uint)prev * 128 + tid) * 2)) = 0; \
      int2 mm_ = meta[(c)*ECH + tid];                                            \
      if (mm_.x >= 0) {                                                          \
        *(ushort*)((char*)S + swz(((uint)mm_.x * 128 + tid) * 2)) =              \
            f2b(__int_as_float(mm_.y));                                          \
        prev = mm_.x;                                                            \
      } else {                                                                   \
        prev = -1;                                                               \
      }                                                                          \
    }                                                                            \
  } while (0)

// split-K MFMA phase: this wave's 2 k-steps over 4 m-tiles x 4 n-tiles
#define MFMAP()                                                                  \
  do {                                                                           \
    _Pragma("unroll") for (int ks = 0; ks < 2; ++ks) {                           \
      uint ko_ = (uint)((kh * 2 + ks) * 32 + kq * 8) * 2;                        \
      bf16x8_t b0_ = *(const bf16x8_t*)((const char*)Vt + swz((uint)(r15)*256 + ko_)); \
      bf16x8_t b1_ = *(const bf16x8_t*)((const char*)Vt +                        \
                                        swz((uint)(16 + r15) * 256 + ko_));      \
      bf16x8_t b2_ = *(const bf16x8_t*)((const char*)Vt +                        \
                                        swz((uint)(32 + r15) * 256 + ko_));      \
      bf16x8_t b3_ = *(const bf16x8_t*)((const char*)Vt +                        \
                                        swz((uint)(48 + r15) * 256 + ko_));      \
      _Pragma("unroll") for (int mt = 0; mt < 4; ++mt) {                         \
        bf16x8_t a_ = *(const bf16x8_t*)((const char*)S +                        \
                                         swz((uint)(mq * 64 + mt * 16 + r15) * 256 + ko_)); \
        acc[mt][0] = __builtin_amdgcn_mfma_f32_16x16x32_bf16(a_, b0_, acc[mt][0], 0, 0, 0); \
        acc[mt][1] = __builtin_amdgcn_mfma_f32_16x16x32_bf16(a_, b1_, acc[mt][1], 0, 0, 0); \
        acc[mt][2] = __builtin_amdgcn_mfma_f32_16x16x32_bf16(a_, b2_, acc[mt][2], 0, 0, 0); \
        acc[mt][3] = __builtin_amdgcn_mfma_f32_16x16x32_bf16(a_, b3_, acc[mt][3], 0, 0, 0); \
      }                                                                          \
    }                                                                            \
  } while (0)

#define LGKM0() asm volatile("s_waitcnt lgkmcnt(0)" ::: "memory")

  f32x4_t acc[4][4];
#pragma unroll
  for (int a = 0; a < 4; ++a)
#pragma unroll
    for (int nt = 0; nt < 4; ++nt) acc[a][nt] = (f32x4_t)(0.0f);

  // prologue: fire chunk 0/1 loads early, then meta + S zero
  LOADC(0, rA);
  if (nch > 1) LOADC(1, rB);
  for (int i = tid; i < 256 * 128 / 2; i += 512) ((uint*)S)[i] = 0u;
  for (int i = tid; i < MAXPER; i += 512) {
    int pb = -1;
    float pw = 0.f;
    if (i < nE) {
      int n = eidx[base + i];
      pw = 1.0f / fmaxf((float)cnt[n], 1.0f);
      pb = batch[n];
    }
    meta[i] = make_int2(pb, __float_as_int(pw));
  }
  int prev = -1;
  __syncthreads();

  for (int c = 0; c < nch; c += 2) {
    PHASEW(c, rA);
    LGKM0();
    __builtin_amdgcn_s_barrier();
    if (c + 2 < nch) LOADC(c + 2, rA);
    MFMAP();
    LGKM0();
    __builtin_amdgcn_s_barrier();
    if (c + 1 < nch) {
      PHASEW(c + 1, rB);
      LGKM0();
      __builtin_amdgcn_s_barrier();
      if (c + 3 < nch) LOADC(c + 3, rB);
      MFMAP();
      LGKM0();
      __builtin_amdgcn_s_barrier();
    }
  }

  // epilogue: merge K-half partials through LDS (S is free now), then store.
  // D layout (16x16x32): col = lane&15, row = (lane>>4)*4 + j  [m89]
  __syncthreads();
  float* Smrg = (float*)S;  // 256*64 f32 = 64KB
  if (kh == 0) {
#pragma unroll
    for (int mt = 0; mt < 4; ++mt)
#pragma unroll
      for (int nt = 0; nt < 4; ++nt)
#pragma unroll
        for (int j = 0; j < 4; ++j)
          Smrg[(mq * 64 + mt * 16 + kq * 4 + j) * 64 + nt * 16 + r15] = acc[mt][nt][j];
  }
  __syncthreads();
  if (kh == 1) {
    float* outp = partial + (size_t)blockIdx.x * GB * DD;
#pragma unroll
    for (int mt = 0; mt < 4; ++mt)
#pragma unroll
      for (int nt = 0; nt < 4; ++nt)
#pragma unroll
        for (int j = 0; j < 4; ++j) {
          int idx = (mq * 64 + mt * 16 + kq * 4 + j) * 64 + nt * 16 + r15;
          outp[idx] = Smrg[idx] + acc[mt][nt][j];
        }
  }
#undef LOADC
#undef PHASEW
#undef MFMAP
#undef LGKM0
}

// ---------------------------------------------------------------------------
// Per-graph: reduce NEB partials + pool x + copy u -> bf16 comb row.
// ---------------------------------------------------------------------------
__global__ __launch_bounds__(256) void k_reduce(const float* __restrict__ partial,
                                                const float* __restrict__ x,
                                                const float* __restrict__ u,
                                                const int* __restrict__ batch,
                                                ushort* __restrict__ comb, int N) {
  __shared__ int s_lo, s_hi;
  __shared__ float rE[4][64], rV[4][64];
  int b = blockIdx.x;
  int tid = threadIdx.x;
  if (tid == 0) {
    int lo = 0, hi = N;
    while (lo < hi) { int m = (lo + hi) >> 1; if (batch[m] < b) lo = m + 1; else hi = m; }
    s_lo = lo;
    hi = N;
    while (lo < hi) { int m = (lo + hi) >> 1; if (batch[m] < b + 1) lo = m + 1; else hi = m; }
    s_hi = lo;
  }
  __syncthreads();
  int lo = s_lo, hi = s_hi;
  int d = tid & 63, sub = tid >> 6;
  float accE = 0.f, accV = 0.f;
  for (int p = sub; p < NEB; p += 4)
    accE += partial[((size_t)p * GB + b) * DD + d];
  for (int n = lo + sub; n < hi; n += 4)
    accV += x[(size_t)n * DD + d];
  rE[sub][d] = accE;
  rV[sub][d] = accV;
  __syncthreads();
  if (sub == 0) {
    float invNb = 1.0f / fmaxf((float)(hi - lo), 1.0f);
    float ue = (rE[0][d] + rE[1][d] + rE[2][d] + rE[3][d]) * invNb;
    float uv = (rV[0][d] + rV[1][d] + rV[2][d] + rV[3][d]) * invNb;
    ushort* row = comb + (size_t)b * 192;
    row[d] = f2b(ue);
    row[64 + d] = f2b(uv);
    row[128 + d] = f2b(u[(size_t)b * DD + d]);
  }
}

// ---------------------------------------------------------------------------
// MFMA MLP: 1 block, 512 threads (8 waves), all weights pre-staged behind one
// barrier. Proven (absmax 0.039 << 0.13).
// ---------------------------------------------------------------------------
template <int K, int WS, bool FIRST, bool LAST>
__device__ __forceinline__ void mlp_layer(int tid, const ushort* __restrict__ combg,
                                          float* hbuf, ushort* a_lds,
                                          const ushort* w_lds, const float* bias_s,
                                          float* ps, float* pq, float* ab, float* bb,
                                          const float* __restrict__ gamma,
                                          const float* __restrict__ beta,
                                          float* __restrict__ out) {
  const int lane = tid & 63, wv = tid >> 6;
  f32x4_t acc[2][4];
#pragma unroll
  for (int a = 0; a < 2; ++a)
#pragma unroll
    for (int nt = 0; nt < 4; ++nt) acc[a][nt] = (f32x4_t)(0.0f);

  const int m0 = wv * 32;
  const int r15 = lane & 15, kq = lane >> 4;
  for (int kk = 0; kk < K; kk += 32) {
    int koff = kk + kq * 8;
    bf16x8_t af[2], bf[4];
    if (FIRST) {
      const ushort* ap = combg + (size_t)(m0 + r15) * 192 + koff;
      af[0] = *reinterpret_cast<const bf16x8_t*>(ap);
      af[1] = *reinterpret_cast<const bf16x8_t*>(ap + 16 * 192);
    } else {
      const ushort* ap = &a_lds[(m0 + r15) * 72 + koff];
      af[0] = *reinterpret_cast<const bf16x8_t*>(ap);
      af[1] = *reinterpret_cast<const bf16x8_t*>(ap + 16 * 72);
    }
#pragma unroll
    for (int nt = 0; nt < 4; ++nt)
      bf[nt] = *reinterpret_cast<const bf16x8_t*>(&w_lds[(nt * 16 + r15) * WS + koff]);
#pragma unroll
    for (int a = 0; a < 2; ++a)
#pragma unroll
      for (int nt = 0; nt < 4; ++nt)
        acc[a][nt] = __builtin_amdgcn_mfma_f32_16x16x32_bf16(af[a], bf[nt], acc[a][nt], 0, 0, 0);
  }

#pragma unroll
  for (int a = 0; a < 2; ++a) {
#pragma unroll
    for (int nt = 0; nt < 4; ++nt) {
      int col = nt * 16 + r15;
#pragma unroll
      for (int j = 0; j < 4; ++j) {
        int row = m0 + a * 16 + kq * 4 + j;
        float v = acc[a][nt][j] + bias_s[col];
        hbuf[row * 65 + col] = fmaxf(v, 0.f);
      }
    }
  }
  __syncthreads();

  {
    int col = tid & 63, seg = tid >> 6;
    float s = 0.f, q = 0.f;
#pragma unroll
    for (int t = 0; t < 32; ++t) {
      float v = hbuf[(seg * 32 + t) * 65 + col];
      s += v;
      q += v * v;
    }
    ps[seg * 64 + col] = s;
    pq[seg * 64 + col] = q;
  }
  __syncthreads();
  if (tid < 64) {
    float s = 0.f, q = 0.f;
#pragma unroll
    for (int g = 0; g < 8; ++g) {
      s += ps[g * 64 + tid];
      q += pq[g * 64 + tid];
    }
    float mu = s * (1.0f / 256.0f);
    float var = q * (1.0f / 256.0f) - mu * mu;
    float rs = rsqrtf(var + 1e-5f);
    float A = gamma[tid] * rs;
    ab[tid] = A;
    bb[tid] = beta[tid] - mu * A;
  }
  __syncthreads();
  for (int i = tid; i < 256 * 64; i += 512) {
    int r = i >> 6, c = i & 63;
    float y = hbuf[r * 65 + c] * ab[c] + bb[c];
    if (LAST)
      out[i] = y;
    else
      a_lds[r * 72 + c] = f2b(y);
  }
  __syncthreads();
}

__global__ __launch_bounds__(512) void k_mlp(const ushort* __restrict__ comb,
                                             const float* W0, const float* b0,
                                             const float* W1, const float* b1,
                                             const float* W2, const float* b2,
                                             const float* g0, const float* be0,
                                             const float* g1, const float* be1,
                                             const float* g2, const float* be2,
                                             float* __restrict__ out) {
  __shared__ __align__(16) float hbuf[256 * 65];    // 66.6 KB
  __shared__ __align__(16) ushort a_lds[256 * 72];  // 36.9 KB
  __shared__ __align__(16) ushort w0s[64 * 200];    // 25.6 KB
  __shared__ __align__(16) ushort w1s[64 * 72];     // 9.2 KB
  __shared__ __align__(16) ushort w2s[64 * 72];     // 9.2 KB
  __shared__ float ps[8 * 64], pq[8 * 64];
  __shared__ float b0s[64], b1s[64], b2s[64], ab[64], bb[64];
  int tid = threadIdx.x;

  for (int i = tid; i < 64 * 192; i += 512) {
    int r = i / 192, c = i - r * 192;
    w0s[r * 200 + c] = f2b(W0[i]);
  }
  for (int i = tid; i < 64 * 64; i += 512) {
    int r = i >> 6, c = i & 63;
    w1s[r * 72 + c] = f2b(W1[i]);
    w2s[r * 72 + c] = f2b(W2[i]);
  }
  if (tid < 64) {
    b0s[tid] = b0[tid];
    b1s[tid] = b1[tid];
    b2s[tid] = b2[tid];
  }
  __syncthreads();

  mlp_layer<192, 200, true, false>(tid, comb, hbuf, a_lds, w0s, b0s, ps, pq, ab, bb,
                                   g0, be0, nullptr);
  mlp_layer<64, 72, false, false>(tid, comb, hbuf, a_lds, w1s, b1s, ps, pq, ab, bb,
                                  g1, be1, nullptr);
  mlp_layer<64, 72, false, true>(tid, comb, hbuf, a_lds, w2s, b2s, ps, pq, ab, bb,
                                 g2, be2, out);
}

extern "C" void kernel_launch(void* const* d_in, const int* in_sizes, int n_in,
                              void* d_out, int out_size, void* d_ws, size_t ws_size,
                              hipStream_t stream) {
  (void)n_in; (void)out_size; (void)ws_size;
  const float* x         = (const float*)d_in[0];
  const float* edge_attr = (const float*)d_in[1];
  const float* u         = (const float*)d_in[2];
  const int*   eidx      = (const int*)d_in[3];  // row 0 = first E entries
  const int*   batch     = (const int*)d_in[4];
  const float* W0 = (const float*)d_in[5];
  const float* b0 = (const float*)d_in[6];
  const float* W1 = (const float*)d_in[7];
  const float* b1 = (const float*)d_in[8];
  const float* W2 = (const float*)d_in[9];
  const float* b2 = (const float*)d_in[10];
  const float* g0 = (const float*)d_in[11];
  const float* be0 = (const float*)d_in[12];
  const float* g1 = (const float*)d_in[13];
  const float* be1 = (const float*)d_in[14];
  const float* g2 = (const float*)d_in[15];
  const float* be2 = (const float*)d_in[16];

  int N = in_sizes[0] / DD;
  int E = in_sizes[1] / DD;

  // ws layout (16B padded): partial[NEB*GB*64] f32 (16.7MB) | cnt[N] | comb
  float* partial = (float*)d_ws;
  int* cnt = (int*)(partial + (size_t)NEB * GB * DD);
  ushort* comb = (ushort*)(cnt + ((N + 3) & ~3));

  k_zero<<<64, 256, 0, stream>>>(cnt, N);
  k_hist<<<1024, 256, 0, stream>>>(eidx, cnt, E);
  k_edgesum<<<NEB, 512, 0, stream>>>(edge_attr, eidx, cnt, batch, partial, E);
  k_reduce<<<256, 256, 0, stream>>>(partial, x, u, batch, comb, N);
  k_mlp<<<1, 512, 0, stream>>>(comb, W0, b0, W1, b1, W2, b2,
                               g0, be0, g1, be1, g2, be2, (float*)d_out);
}